// Round 1
// baseline (744.846 us; speedup 1.0000x reference)
//
#include <hip/hip_runtime.h>
#include <hip/hip_bf16.h>
#include <cstdint>
#include <cstddef>

#define VV 50000
#define HH 1024
#define NROWS 4096
#define VPAD 50048      // 391*128
#define NCOLT 391
#define NCHUNK 782      // 391*2 (64-col chunks)
#define SP1 4000
#define SP2 20000
#define SP3 50000
#define VTOT 50002      // 50000 + 2 tail-cluster columns

typedef __attribute__((ext_vector_type(8))) short short8;
typedef __attribute__((ext_vector_type(4))) float f32x4;
typedef __attribute__((ext_vector_type(4))) unsigned short us4;

typedef __attribute__((address_space(1))) unsigned int uint_g;
typedef __attribute__((address_space(3))) unsigned int uint_l;

__device__ __forceinline__ void gload16(const void* g, void* l) {
  __builtin_amdgcn_global_load_lds((const uint_g*)g, (uint_l*)l, 16, 0, 0);
}

__device__ __forceinline__ unsigned short f2bf(float f) {
  __hip_bfloat16 h = __float2bfloat16(f);
  return *reinterpret_cast<unsigned short*>(&h);
}

// ---- convert weight + tail_vectors -> bf16, padded to VPAD rows ----
__global__ void convW(const float* __restrict__ w, const float* __restrict__ tails,
                      unsigned short* __restrict__ Wb) {
  const size_t nq = (size_t)VPAD * HH / 4;
  for (size_t q = (size_t)blockIdx.x * blockDim.x + threadIdx.x; q < nq;
       q += (size_t)gridDim.x * blockDim.x) {
    const size_t e = q * 4;
    const int row = (int)(e >> 10);
    us4 o;
    if (row < VV) {
      float4 f = *(const float4*)(w + e);
      o = (us4){f2bf(f.x), f2bf(f.y), f2bf(f.z), f2bf(f.w)};
    } else if (row < VTOT) {
      float4 f = *(const float4*)(tails + (e - (size_t)VV * HH));
      o = (us4){f2bf(f.x), f2bf(f.y), f2bf(f.z), f2bf(f.w)};
    } else {
      o = (us4){0, 0, 0, 0};
    }
    *(us4*)(Wb + e) = o;
  }
}

__global__ void convH(const float* __restrict__ h, unsigned short* __restrict__ Hb) {
  const size_t nq = (size_t)NROWS * HH / 4;
  for (size_t q = (size_t)blockIdx.x * blockDim.x + threadIdx.x; q < nq;
       q += (size_t)gridDim.x * blockDim.x) {
    const size_t e = q * 4;
    float4 f = *(const float4*)(h + e);
    us4 o = (us4){f2bf(f.x), f2bf(f.y), f2bf(f.z), f2bf(f.w)};
    *(us4*)(Hb + e) = o;
  }
}

// ---- main GEMM + segment-partial-sumexp epilogue ----
// grid (32 rowTiles, 391 colTiles), 256 threads (4 waves, 2x2 of 64x64)
__global__ __launch_bounds__(256) void gemm_lse(
    const unsigned short* __restrict__ Wb, const unsigned short* __restrict__ Hb,
    const float* __restrict__ bias, const float* __restrict__ tail_bias,
    float* __restrict__ partials /* [3][NROWS][NCHUNK] */) {
  __shared__ __align__(16) unsigned short As[128 * 64];
  __shared__ __align__(16) unsigned short Bs[128 * 64];
  const int tid = threadIdx.x;
  const int w = tid >> 6, lane = tid & 63;
  const int rowTile = blockIdx.x, colTile = blockIdx.y;
  const unsigned short* Ag = Hb + (size_t)rowTile * 128 * HH;
  const unsigned short* Bg = Wb + (size_t)colTile * 128 * HH;

  f32x4 acc[4][4];
#pragma unroll
  for (int i = 0; i < 4; i++)
#pragma unroll
    for (int j = 0; j < 4; j++) acc[i][j] = (f32x4){0.f, 0.f, 0.f, 0.f};

  const int wr = w >> 1, wc = w & 1;
  const int fr = lane & 15, fq = lane >> 4;

  for (int kt = 0; kt < HH / 64; ++kt) {
    const int k0 = kt * 64;
#pragma unroll
    for (int i = 0; i < 4; i++) {
      const int e = ((i * 4 + w) * 64 + lane) * 8;  // element index in [128][64] tile
      const int r = e >> 6, c = e & 63;
      gload16(Ag + (size_t)r * HH + k0 + c, As + e);
      gload16(Bg + (size_t)r * HH + k0 + c, Bs + e);
    }
    __syncthreads();
#pragma unroll
    for (int kk = 0; kk < 2; ++kk) {
      const int K0 = kk * 32 + fq * 8;
      short8 a[4], b[4];
#pragma unroll
      for (int mi = 0; mi < 4; mi++)
        a[mi] = *(const short8*)&As[(wr * 64 + mi * 16 + fr) * 64 + K0];
#pragma unroll
      for (int ni = 0; ni < 4; ni++)
        b[ni] = *(const short8*)&Bs[(wc * 64 + ni * 16 + fr) * 64 + K0];
#pragma unroll
      for (int mi = 0; mi < 4; mi++)
#pragma unroll
        for (int ni = 0; ni < 4; ni++)
          acc[mi][ni] =
              __builtin_amdgcn_mfma_f32_16x16x32_bf16(a[mi], b[ni], acc[mi][ni], 0, 0, 0);
    }
    __syncthreads();
  }

  // ---- epilogue: per-(row, 64-col chunk, segment) sum of exp(logit + bias) ----
  const int colw = colTile * 128 + wc * 64;  // wave's col base
  float biasv[4], validf[4];
  int segv[4];
#pragma unroll
  for (int ni = 0; ni < 4; ni++) {
    const int col = colw + ni * 16 + fr;
    const bool valid = col < VTOT;
    float b = 0.f;
    if (col < VV) b = bias[col];
    else if (valid) b = tail_bias[col - VV];
    biasv[ni] = b;
    segv[ni] = (col < SP1) ? 0 : (col < SP2) ? 1 : (col < SP3) ? 2 : 0;
    validf[ni] = valid ? 1.f : 0.f;
  }
  const int segLo = (colw < SP1) ? 0 : (colw < SP2) ? 1 : (colw < SP3) ? 2 : 0;
  const int colHi = colw + 63;
  const int segHi = (colHi < SP1) ? 0 : (colHi < SP2) ? 1 : (colHi < SP3) ? 2 : 0;
  const bool oneseg = (segLo == segHi) && (colHi < VTOT);

  const int chunk = colTile * 2 + wc;
  const size_t segStride = (size_t)NROWS * NCHUNK;

#pragma unroll
  for (int mi = 0; mi < 4; mi++) {
    const int rowg = rowTile * 128 + wr * 64 + mi * 16 + fq * 4;
    if (oneseg) {
#pragma unroll
      for (int r = 0; r < 4; r++) {
        float p = 0.f;
#pragma unroll
        for (int ni = 0; ni < 4; ni++)
          p += validf[ni] * __expf(acc[mi][ni][r] + biasv[ni]);
#pragma unroll
        for (int m = 1; m < 16; m <<= 1) p += __shfl_xor(p, m);
        if (fr == 0) {
          const size_t base = (size_t)(rowg + r) * NCHUNK + chunk;
          partials[(size_t)segLo * segStride + base] = p;
          partials[(size_t)((segLo + 1) % 3) * segStride + base] = 0.f;
          partials[(size_t)((segLo + 2) % 3) * segStride + base] = 0.f;
        }
      }
    } else {
#pragma unroll
      for (int r = 0; r < 4; r++) {
        float p0 = 0.f, p1 = 0.f, p2 = 0.f;
#pragma unroll
        for (int ni = 0; ni < 4; ni++) {
          const float e = validf[ni] * __expf(acc[mi][ni][r] + biasv[ni]);
          p0 += (segv[ni] == 0) ? e : 0.f;
          p1 += (segv[ni] == 1) ? e : 0.f;
          p2 += (segv[ni] == 2) ? e : 0.f;
        }
#pragma unroll
        for (int m = 1; m < 16; m <<= 1) {
          p0 += __shfl_xor(p0, m);
          p1 += __shfl_xor(p1, m);
          p2 += __shfl_xor(p2, m);
        }
        if (fr == 0) {
          const size_t base = (size_t)(rowg + r) * NCHUNK + chunk;
          partials[0 * segStride + base] = p0;
          partials[1 * segStride + base] = p1;
          partials[2 * segStride + base] = p2;
        }
      }
    }
  }
}

// ---- per-row: combine chunk partials, compute selected logits in fp32, loss ----
__global__ __launch_bounds__(256) void rowloss(
    const float* __restrict__ partials, const float* __restrict__ hiddens,
    const float* __restrict__ weight, const float* __restrict__ bias,
    const float* __restrict__ tails, const float* __restrict__ tail_bias,
    const int* __restrict__ targets, float* __restrict__ losses) {
  const int row = blockIdx.x * 4 + (threadIdx.x >> 6);
  const int lane = threadIdx.x & 63;
  const size_t segStride = (size_t)NROWS * NCHUNK;
  const float* P0 = partials + (size_t)row * NCHUNK;
  const float* P1 = P0 + segStride;
  const float* P2 = P1 + segStride;
  float s0 = 0.f, s1 = 0.f, s2 = 0.f;
  for (int c = lane; c < NCHUNK; c += 64) {
    s0 += P0[c];
    s1 += P1[c];
    s2 += P2[c];
  }
#pragma unroll
  for (int m = 1; m < 64; m <<= 1) {
    s0 += __shfl_xor(s0, m);
    s1 += __shfl_xor(s1, m);
    s2 += __shfl_xor(s2, m);
  }
  const int t = targets[row];
  const int cl = (t >= SP1) + (t >= SP2);
  const float* hv = hiddens + (size_t)row * HH;
  const float* w1;
  float b1;
  if (cl == 0) {
    w1 = weight + (size_t)t * HH;
    b1 = bias[t];
  } else if (cl == 1) {
    w1 = tails + HH;  // head col 4001 <-> tail_vectors[1]
    b1 = tail_bias[1];
  } else {
    w1 = tails;       // head col 4000 <-> tail_vectors[0]
    b1 = tail_bias[0];
  }
  float d1 = 0.f, d2 = 0.f;
  for (int i = lane; i < HH; i += 64) d1 += hv[i] * w1[i];
  if (cl > 0) {
    const float* w2 = weight + (size_t)t * HH;
    for (int i = lane; i < HH; i += 64) d2 += hv[i] * w2[i];
  }
#pragma unroll
  for (int m = 1; m < 64; m <<= 1) {
    d1 += __shfl_xor(d1, m);
    d2 += __shfl_xor(d2, m);
  }
  if (lane == 0) {
    float loss = logf(s0) - (d1 + b1);
    if (cl == 1) loss += logf(s1) - (d2 + bias[t]);
    if (cl == 2) loss += logf(s2) - (d2 + bias[t]);
    losses[row] = loss;
  }
}

__global__ void meanloss(const float* __restrict__ losses, float* __restrict__ out) {
  __shared__ float red[256];
  float s = 0.f;
  for (int i = threadIdx.x; i < NROWS; i += 256) s += losses[i];
  red[threadIdx.x] = s;
  __syncthreads();
  for (int st = 128; st > 0; st >>= 1) {
    if ((int)threadIdx.x < st) red[threadIdx.x] += red[threadIdx.x + st];
    __syncthreads();
  }
  if (threadIdx.x == 0) out[0] = red[0] / (float)NROWS;
}

extern "C" void kernel_launch(void* const* d_in, const int* in_sizes, int n_in,
                              void* d_out, int out_size, void* d_ws, size_t ws_size,
                              hipStream_t stream) {
  const float* weight = (const float*)d_in[0];
  const float* bias = (const float*)d_in[1];
  const float* hiddens = (const float*)d_in[2];
  const float* tails = (const float*)d_in[3];
  const float* tail_bias = (const float*)d_in[4];
  const int* targets = (const int*)d_in[5];
  float* out = (float*)d_out;

  char* ws = (char*)d_ws;
  unsigned short* Wb = (unsigned short*)ws;                    // 50048*1024*2 = 102,498,304 B
  unsigned short* Hb = (unsigned short*)(ws + 102498304);      // 4096*1024*2  =   8,388,608 B
  float* partials = (float*)(ws + 110886912);                  // 3*4096*782*4 =  38,436,864 B
  float* losses = (float*)(ws + 149323776);                    // 4096*4       =      16,384 B

  hipLaunchKernelGGL(convW, dim3(2048), dim3(256), 0, stream, weight, tails, Wb);
  hipLaunchKernelGGL(convH, dim3(512), dim3(256), 0, stream, hiddens, Hb);
  hipLaunchKernelGGL(gemm_lse, dim3(32, NCOLT), dim3(256), 0, stream, Wb, Hb, bias,
                     tail_bias, partials);
  hipLaunchKernelGGL(rowloss, dim3(NROWS / 4), dim3(256), 0, stream, partials, hiddens,
                     weight, bias, tails, tail_bias, targets, losses);
  hipLaunchKernelGGL(meanloss, dim3(1), dim3(256), 0, stream, losses, out);
}

// Round 2
// 556.301 us; speedup vs baseline: 1.3389x; 1.3389x over previous
//
#include <hip/hip_runtime.h>
#include <hip/hip_bf16.h>
#include <cstdint>
#include <cstddef>

#define VV 50000
#define HH 1024
#define NROWS 4096
#define VPAD 50048      // 391*128
#define NCOLT 391
#define NCHUNK 782      // 50048/64
#define SP1 4000
#define SP2 20000
#define SP3 50000
#define VTOT 50002      // 50000 + 2 tail-cluster columns

#define BM 256
#define BN 128
#define BK 64
#define NKT (HH / BK)           // 16
#define A_SLOT_E (BM * BK)      // 16384 elems
#define B_SLOT_E (BN * BK)      // 8192 elems
#define SLOT_E (A_SLOT_E + B_SLOT_E)  // 24576 elems = 48 KiB

typedef __attribute__((ext_vector_type(8))) short short8;
typedef __attribute__((ext_vector_type(4))) float f32x4;
typedef __attribute__((ext_vector_type(4))) unsigned short us4;

typedef __attribute__((address_space(1))) unsigned int uint_g;
typedef __attribute__((address_space(3))) unsigned int uint_l;

__device__ __forceinline__ void gload16(const void* g, void* l) {
  __builtin_amdgcn_global_load_lds((const uint_g*)g, (uint_l*)l, 16, 0, 0);
}

__device__ __forceinline__ unsigned short f2bf(float f) {
  __hip_bfloat16 h = __float2bfloat16(f);
  return *reinterpret_cast<unsigned short*>(&h);
}

// ---- convert weight + tail_vectors -> bf16, padded to VPAD rows ----
__global__ void convW(const float* __restrict__ w, const float* __restrict__ tails,
                      unsigned short* __restrict__ Wb) {
  const size_t nq = (size_t)VPAD * HH / 4;
  for (size_t q = (size_t)blockIdx.x * blockDim.x + threadIdx.x; q < nq;
       q += (size_t)gridDim.x * blockDim.x) {
    const size_t e = q * 4;
    const int row = (int)(e >> 10);
    us4 o;
    if (row < VV) {
      float4 f = *(const float4*)(w + e);
      o = (us4){f2bf(f.x), f2bf(f.y), f2bf(f.z), f2bf(f.w)};
    } else if (row < VTOT) {
      float4 f = *(const float4*)(tails + (e - (size_t)VV * HH));
      o = (us4){f2bf(f.x), f2bf(f.y), f2bf(f.z), f2bf(f.w)};
    } else {
      o = (us4){0, 0, 0, 0};
    }
    *(us4*)(Wb + e) = o;
  }
}

__global__ void convH(const float* __restrict__ h, unsigned short* __restrict__ Hb) {
  const size_t nq = (size_t)NROWS * HH / 4;
  for (size_t q = (size_t)blockIdx.x * blockDim.x + threadIdx.x; q < nq;
       q += (size_t)gridDim.x * blockDim.x) {
    const size_t e = q * 4;
    float4 f = *(const float4*)(h + e);
    us4 o = (us4){f2bf(f.x), f2bf(f.y), f2bf(f.z), f2bf(f.w)};
    *(us4*)(Hb + e) = o;
  }
}

// ---- main GEMM + segment-partial-sumexp epilogue ----
// grid (16 rowTiles, 391 colTiles), 512 threads (8 waves = 4M x 2N, per-wave 64x64)
// 3-slot LDS ring, distance-2 prefetch, counted vmcnt, XOR-swizzled tiles.
__global__ __launch_bounds__(512) void gemm_lse(
    const unsigned short* __restrict__ Wb, const unsigned short* __restrict__ Hb,
    const float* __restrict__ bias, const float* __restrict__ tail_bias,
    float* __restrict__ partials /* [3][NROWS][NCHUNK] */) {
  __shared__ __align__(16) unsigned short lds[3 * SLOT_E];  // 147456 B

  const int tid = threadIdx.x;
  const int w = tid >> 6, lane = tid & 63;
  const int wr = w >> 1, wc = w & 1;
  const int fr = lane & 15, fq = lane >> 4;
  const int rowTile = blockIdx.x, colTile = blockIdx.y;
  const unsigned short* Ag = Hb + (size_t)rowTile * BM * HH;
  const unsigned short* Bg = Wb + (size_t)colTile * BN * HH;

  // staging offsets: linear LDS dest, inverse-swizzled global source
  int srcA[4], srcB[2];
  const int dcb = (tid & 7) << 4;  // dest byte-col within 128B row
#pragma unroll
  for (int i = 0; i < 4; i++) {
    const int R = (i * 512 + tid) >> 3;
    srcA[i] = R * HH + ((dcb ^ ((R & 7) << 4)) >> 1);
  }
#pragma unroll
  for (int i = 0; i < 2; i++) {
    const int R = (i * 512 + tid) >> 3;
    srcB[i] = R * HH + ((dcb ^ ((R & 7) << 4)) >> 1);
  }

  // fragment read offsets (swizzled), elements within slot
  int offA[4][2], offB[4][2];
#pragma unroll
  for (int mi = 0; mi < 4; mi++) {
    const int R = wr * 64 + mi * 16 + fr;
#pragma unroll
    for (int kk = 0; kk < 2; kk++) {
      const int cb = kk * 64 + fq * 16;
      offA[mi][kk] = R * 64 + ((cb ^ ((R & 7) << 4)) >> 1);
    }
  }
#pragma unroll
  for (int ni = 0; ni < 4; ni++) {
    const int R = wc * 64 + ni * 16 + fr;
#pragma unroll
    for (int kk = 0; kk < 2; kk++) {
      const int cb = kk * 64 + fq * 16;
      offB[ni][kk] = R * 64 + ((cb ^ ((R & 7) << 4)) >> 1);
    }
  }

  f32x4 acc[4][4];
#pragma unroll
  for (int i = 0; i < 4; i++)
#pragma unroll
    for (int j = 0; j < 4; j++) acc[i][j] = (f32x4){0.f, 0.f, 0.f, 0.f};

  auto STAGE = [&](int t) {
    const int slot = t % 3;
    unsigned short* Asl = (unsigned short*)lds + slot * SLOT_E;
    unsigned short* Bsl = Asl + A_SLOT_E;
    const int k0 = t * BK;
#pragma unroll
    for (int i = 0; i < 4; i++)
      gload16(Ag + (size_t)srcA[i] + k0, Asl + (i * 512 + tid) * 8);
#pragma unroll
    for (int i = 0; i < 2; i++)
      gload16(Bg + (size_t)srcB[i] + k0, Bsl + (i * 512 + tid) * 8);
  };

  STAGE(0);
  STAGE(1);

  for (int t = 0; t < NKT; ++t) {
    if (t < NKT - 1)
      asm volatile("s_waitcnt vmcnt(6)" ::: "memory");
    else
      asm volatile("s_waitcnt vmcnt(0)" ::: "memory");
    __builtin_amdgcn_s_barrier();
    if (t + 2 < NKT) STAGE(t + 2);

    const unsigned short* Asl = (const unsigned short*)lds + (t % 3) * SLOT_E;
    const unsigned short* Bsl = Asl + A_SLOT_E;
#pragma unroll
    for (int kk = 0; kk < 2; kk++) {
      short8 a[4], b[4];
#pragma unroll
      for (int mi = 0; mi < 4; mi++) a[mi] = *(const short8*)&Asl[offA[mi][kk]];
#pragma unroll
      for (int ni = 0; ni < 4; ni++) b[ni] = *(const short8*)&Bsl[offB[ni][kk]];
      __builtin_amdgcn_s_setprio(1);
#pragma unroll
      for (int mi = 0; mi < 4; mi++)
#pragma unroll
        for (int ni = 0; ni < 4; ni++)
          acc[mi][ni] =
              __builtin_amdgcn_mfma_f32_16x16x32_bf16(a[mi], b[ni], acc[mi][ni], 0, 0, 0);
      __builtin_amdgcn_s_setprio(0);
    }
  }

  // ---- epilogue: per-(row, 64-col chunk, segment) sum of exp(logit + bias) ----
  const int colw = colTile * BN + wc * 64;  // wave's col base
  float biasv[4], validf[4];
  int segv[4];
#pragma unroll
  for (int ni = 0; ni < 4; ni++) {
    const int col = colw + ni * 16 + fr;
    const bool valid = col < VTOT;
    float b = 0.f;
    if (col < VV) b = bias[col];
    else if (valid) b = tail_bias[col - VV];
    biasv[ni] = b;
    segv[ni] = (col < SP1) ? 0 : (col < SP2) ? 1 : (col < SP3) ? 2 : 0;
    validf[ni] = valid ? 1.f : 0.f;
  }
  const int segLo = (colw < SP1) ? 0 : (colw < SP2) ? 1 : (colw < SP3) ? 2 : 0;
  const int colHi = colw + 63;
  const int segHi = (colHi < SP1) ? 0 : (colHi < SP2) ? 1 : (colHi < SP3) ? 2 : 0;
  const bool oneseg = (segLo == segHi) && (colHi < VTOT);

  const int chunk = colTile * 2 + wc;
  const size_t segStride = (size_t)NROWS * NCHUNK;

#pragma unroll
  for (int mi = 0; mi < 4; mi++) {
    const int rowg = rowTile * BM + wr * 64 + mi * 16 + fq * 4;
    if (oneseg) {
#pragma unroll
      for (int r = 0; r < 4; r++) {
        float p = 0.f;
#pragma unroll
        for (int ni = 0; ni < 4; ni++)
          p += validf[ni] * __expf(acc[mi][ni][r] + biasv[ni]);
#pragma unroll
        for (int m = 1; m < 16; m <<= 1) p += __shfl_xor(p, m);
        if (fr == 0) {
          const size_t base = (size_t)(rowg + r) * NCHUNK + chunk;
          partials[(size_t)segLo * segStride + base] = p;
          partials[(size_t)((segLo + 1) % 3) * segStride + base] = 0.f;
          partials[(size_t)((segLo + 2) % 3) * segStride + base] = 0.f;
        }
      }
    } else {
#pragma unroll
      for (int r = 0; r < 4; r++) {
        float p0 = 0.f, p1 = 0.f, p2 = 0.f;
#pragma unroll
        for (int ni = 0; ni < 4; ni++) {
          const float e = validf[ni] * __expf(acc[mi][ni][r] + biasv[ni]);
          p0 += (segv[ni] == 0) ? e : 0.f;
          p1 += (segv[ni] == 1) ? e : 0.f;
          p2 += (segv[ni] == 2) ? e : 0.f;
        }
#pragma unroll
        for (int m = 1; m < 16; m <<= 1) {
          p0 += __shfl_xor(p0, m);
          p1 += __shfl_xor(p1, m);
          p2 += __shfl_xor(p2, m);
        }
        if (fr == 0) {
          const size_t base = (size_t)(rowg + r) * NCHUNK + chunk;
          partials[0 * segStride + base] = p0;
          partials[1 * segStride + base] = p1;
          partials[2 * segStride + base] = p2;
        }
      }
    }
  }
}

// ---- per-row: combine chunk partials, compute selected logits in fp32, loss ----
__global__ __launch_bounds__(256) void rowloss(
    const float* __restrict__ partials, const float* __restrict__ hiddens,
    const float* __restrict__ weight, const float* __restrict__ bias,
    const float* __restrict__ tails, const float* __restrict__ tail_bias,
    const int* __restrict__ targets, float* __restrict__ losses) {
  const int row = blockIdx.x * 4 + (threadIdx.x >> 6);
  const int lane = threadIdx.x & 63;
  const size_t segStride = (size_t)NROWS * NCHUNK;
  const float* P0 = partials + (size_t)row * NCHUNK;
  const float* P1 = P0 + segStride;
  const float* P2 = P1 + segStride;
  float s0 = 0.f, s1 = 0.f, s2 = 0.f;
  for (int c = lane; c < NCHUNK; c += 64) {
    s0 += P0[c];
    s1 += P1[c];
    s2 += P2[c];
  }
#pragma unroll
  for (int m = 1; m < 64; m <<= 1) {
    s0 += __shfl_xor(s0, m);
    s1 += __shfl_xor(s1, m);
    s2 += __shfl_xor(s2, m);
  }
  const int t = targets[row];
  const int cl = (t >= SP1) + (t >= SP2);
  const float* hv = hiddens + (size_t)row * HH;
  const float* w1;
  float b1;
  if (cl == 0) {
    w1 = weight + (size_t)t * HH;
    b1 = bias[t];
  } else if (cl == 1) {
    w1 = tails + HH;  // head col 4001 <-> tail_vectors[1]
    b1 = tail_bias[1];
  } else {
    w1 = tails;       // head col 4000 <-> tail_vectors[0]
    b1 = tail_bias[0];
  }
  float d1 = 0.f, d2 = 0.f;
  for (int i = lane; i < HH; i += 64) d1 += hv[i] * w1[i];
  if (cl > 0) {
    const float* w2 = weight + (size_t)t * HH;
    for (int i = lane; i < HH; i += 64) d2 += hv[i] * w2[i];
  }
#pragma unroll
  for (int m = 1; m < 64; m <<= 1) {
    d1 += __shfl_xor(d1, m);
    d2 += __shfl_xor(d2, m);
  }
  if (lane == 0) {
    float loss = logf(s0) - (d1 + b1);
    if (cl == 1) loss += logf(s1) - (d2 + bias[t]);
    if (cl == 2) loss += logf(s2) - (d2 + bias[t]);
    losses[row] = loss;
  }
}

__global__ void meanloss(const float* __restrict__ losses, float* __restrict__ out) {
  __shared__ float red[256];
  float s = 0.f;
  for (int i = threadIdx.x; i < NROWS; i += 256) s += losses[i];
  red[threadIdx.x] = s;
  __syncthreads();
  for (int st = 128; st > 0; st >>= 1) {
    if ((int)threadIdx.x < st) red[threadIdx.x] += red[threadIdx.x + st];
    __syncthreads();
  }
  if (threadIdx.x == 0) out[0] = red[0] / (float)NROWS;
}

extern "C" void kernel_launch(void* const* d_in, const int* in_sizes, int n_in,
                              void* d_out, int out_size, void* d_ws, size_t ws_size,
                              hipStream_t stream) {
  const float* weight = (const float*)d_in[0];
  const float* bias = (const float*)d_in[1];
  const float* hiddens = (const float*)d_in[2];
  const float* tails = (const float*)d_in[3];
  const float* tail_bias = (const float*)d_in[4];
  const int* targets = (const int*)d_in[5];
  float* out = (float*)d_out;

  char* ws = (char*)d_ws;
  unsigned short* Wb = (unsigned short*)ws;                    // 50048*1024*2 = 102,498,304 B
  unsigned short* Hb = (unsigned short*)(ws + 102498304);      // 4096*1024*2  =   8,388,608 B
  float* partials = (float*)(ws + 110886912);                  // 3*4096*782*4 =  38,436,864 B
  float* losses = (float*)(ws + 149323776);                    // 4096*4       =      16,384 B

  hipLaunchKernelGGL(convW, dim3(2048), dim3(256), 0, stream, weight, tails, Wb);
  hipLaunchKernelGGL(convH, dim3(512), dim3(256), 0, stream, hiddens, Hb);
  hipLaunchKernelGGL(gemm_lse, dim3(NROWS / BM, NCOLT), dim3(512), 0, stream, Wb, Hb,
                     bias, tail_bias, partials);
  hipLaunchKernelGGL(rowloss, dim3(NROWS / 4), dim3(256), 0, stream, partials, hiddens,
                     weight, bias, tails, tail_bias, targets, losses);
  hipLaunchKernelGGL(meanloss, dim3(1), dim3(256), 0, stream, losses, out);
}